// Round 8
// baseline (155.757 us; speedup 1.0000x reference)
//
#include <hip/hip_runtime.h>
#include <hip/hip_fp16.h>
#include <math.h>

#define BB 2
#define CC 64
#define HH 256
#define WW 256
#define KK 9
#define NOFF 10          // offset channels needed (0..8 sampled, 9 completes GN group 4)
#define HW (HH*WW)

typedef __attribute__((ext_vector_type(8))) short s16x8;   // 8 fp16 = 4 VGPRs (MFMA A/B frag)
typedef __attribute__((ext_vector_type(4))) float f32x4;   // MFMA C/D frag

// lerp two packed-fp16 pairs: d = a + fy*(b-a)   (2 VALU: v_pk_sub + v_pk_fma)
__device__ __forceinline__ unsigned lerp2h(unsigned a, unsigned b, __half2 fy2) {
    __half2 ah = *(__half2*)&a, bh = *(__half2*)&b;
    __half2 d = __hfma2(fy2, __hsub2(bh, ah), ah);
    return *(unsigned*)&d;
}

// fast tanh: 1 - 2/(2^(x*2*log2e)+1); v_exp_f32 + v_rcp_f32, saturates correctly
__device__ __forceinline__ float fast_tanh(float z) {
    float e = __builtin_amdgcn_exp2f(z * 2.885390081777927f);
    return 1.f - 2.f * __builtin_amdgcn_rcpf(e + 1.f);
}

// XCD band swizzle: assume xcd = blockIdx % 8 (round-robin dispatch). Give each
// XCD a contiguous 64-row h-band so its resident blocks share a small rolling
// row window in its private 4 MB L2. Decode: W = xcd*256 + i -> (b, h, wt).
__device__ __forceinline__ void swizzle_bhw(int g, int& b, int& h, int& wt) {
    int W = ((g & 7) << 8) | (g >> 3);
    b  = W >> 10;
    int rem = W & 1023;
    h  = rem >> 2;
    wt = rem & 3;
}

// Banked GN accumulators: slot = (b<<6)|bank, 32 floats (128B line) per slot.
// 2048 blocks / 2 b / 64 banks = 16 same-address atomics per dispatch -> hidden.

// tmph layout: [b][h][wblk=w>>2][co][w&3] fp16 -> 8B cell per (wblk,co).
// A 16-lane quad group stores 16 consecutive co cells = one FULL 128B line.

// R5: (256,2) fixed the (256,4)-induced spill (WRITE 187->16.9 MB, confirmed).
// R7: 4x16px rounds cut LDS to 22.1KB, but Occupancy stayed pinned at 23%
//     (2 blk/CU) despite resources allowing 4 -> the waves-per-eu annotation
//     itself is the suspect cap.
// R8: drop the 2nd launch_bounds arg on both MFMA kernels. No forced budget
//     (demand ~72-80 VGPR, no spill pressure); residency becomes resource-
//     determined: min(VGPR 4, LDS 7) = 4 blk/CU.

// ---------------- transpose x: NCHW fp32 -> NHWC fp16 ; blocks >= 2048 pack weights + zero sums ----------------
__global__ __launch_bounds__(256) void transpose_x_kernel(const float* __restrict__ x,
                                                          unsigned short* __restrict__ xTh,
                                                          const float* __restrict__ w_off,
                                                          const float* __restrict__ w_dsc,
                                                          unsigned short* __restrict__ woffB,
                                                          unsigned short* __restrict__ wdscB,
                                                          float* __restrict__ sums_off,
                                                          float* __restrict__ sums_out) {
    if (blockIdx.x >= 2048) {            // ---- weight packing (144 blocks) ----
        int idx = (blockIdx.x - 2048) * 256 + threadIdx.x;
        if (blockIdx.x == 2048) {        // zero banked GN accumulators (ws is poisoned)
            int t = threadIdx.x;
            for (int i = t; i < 128 * 32; i += 256) sums_off[i] = 0.f;
            for (int i = t; i < 128 * 32; i += 256) sums_out[i] = 0.f;
        }
        if (idx < 18 * 64 * 8) {
            int kb = idx >> 9;
            int L  = (idx >> 3) & 63;
            int j  = idx & 7;
            int n = L & 15, quad = L >> 4;
            int kk = kb * 32 + quad * 8 + j;
            int tap = kk >> 6, ci = kk & 63;
            float v = (n < NOFF) ? w_off[(n * 64 + ci) * 9 + tap] : 0.f;
            __half hv = __float2half(v);
            woffB[idx] = *(unsigned short*)&hv;
        }
        if (idx < 4 * 18 * 64 * 8) {
            int nt = idx / 9216;
            int r  = idx - nt * 9216;
            int kb = r >> 9;
            int L  = (r >> 3) & 63;
            int j  = r & 7;
            int n = L & 15, quad = L >> 4;
            int co = nt * 16 + n;
            int kk = kb * 32 + quad * 8 + j;
            int k = kk >> 6, ci = kk & 63;
            __half hv = __float2half(w_dsc[(co * 64 + ci) * 9 + k]);
            wdscB[idx] = *(unsigned short*)&hv;
        }
        return;
    }
    __shared__ float tile[64 * 65];      // [w][c] pitch 65
    int wt = blockIdx.x & 3;
    int h  = (blockIdx.x >> 2) & 255;
    int b  = blockIdx.x >> 10;
    int w0 = wt * 64;
    int t  = threadIdx.x;
    {   // load: float4 over w (16 lanes * 16B = 256B contiguous; wave = 1KB/instr)
        int wq = t & 15, c0 = t >> 4;
#pragma unroll
        for (int it = 0; it < 4; ++it) {
            int c = c0 + it * 16;
            float4 v = *(const float4*)&x[(((b * CC + c) * HH + h) * WW) + w0 + wq * 4];
            tile[(wq * 4 + 0) * 65 + c] = v.x;
            tile[(wq * 4 + 1) * 65 + c] = v.y;
            tile[(wq * 4 + 2) * 65 + c] = v.z;
            tile[(wq * 4 + 3) * 65 + c] = v.w;
        }
    }
    __syncthreads();
    {   // store: uint4 = 8 fp16 channels per thread (8 lanes * 16B = 128B contiguous)
        int c8 = t & 7, wr = t >> 3;
        uint4* dst = (uint4*)xTh;
#pragma unroll
        for (int it = 0; it < 2; ++it) {
            int wl = wr + it * 32;
            const float* row = &tile[wl * 65 + c8 * 8];
            __half2 p0 = __floats2half2_rn(row[0], row[1]);
            __half2 p1 = __floats2half2_rn(row[2], row[3]);
            __half2 p2 = __floats2half2_rn(row[4], row[5]);
            __half2 p3 = __floats2half2_rn(row[6], row[7]);
            uint4 d;
            d.x = *(unsigned*)&p0; d.y = *(unsigned*)&p1;
            d.z = *(unsigned*)&p2; d.w = *(unsigned*)&p3;
            dst[((size_t)((b * HH + h) * WW) + w0 + wl) * 8 + c8] = d;
        }
    }
}

// ---------------- offset conv 3x3 via MFMA, LDS-staged halo strip; GN sums via banked atomics ----------------
#define CPITCH 72   // halves per pixel in conv LDS (16B-aligned, 2-way-free bank phase)
__global__ __launch_bounds__(256) void conv_off_mfma(const unsigned short* __restrict__ xTh,
                                                     const unsigned short* __restrict__ woffB,
                                                     const float* __restrict__ b_off,
                                                     unsigned short* __restrict__ off_raw,
                                                     float* __restrict__ sums_off) {
    __shared__ unsigned short sx[3 * 66 * CPITCH];   // 28,512 B
    __shared__ float rs[4][16], rs2[4][16];
    int t = threadIdx.x;
    int L = t & 63, v = t >> 6;
    int b, h, wt;
    swizzle_bhw(blockIdx.x, b, h, wt);
    int w0 = wt << 6;
    int col = L & 15, quad = L >> 4;

    // stage rows h-1..h+1, cols w0-1..w0+64, 64 ch fp16, zero-padded OOB
#pragma unroll
    for (int it = 0; it < 7; ++it) {
        int linear = it * 256 + t;
        if (linear < 1584) {                     // 3*66*8 chunk-items
            int dy  = linear / 528;
            int rem = linear - dy * 528;
            int px  = rem >> 3, cg = rem & 7;
            int y  = h - 1 + dy;
            int xc = w0 - 1 + px;
            uint4 d = make_uint4(0, 0, 0, 0);
            if ((unsigned)y < 256u && (unsigned)xc < 256u)
                d = *(const uint4*)(xTh + ((size_t)(((b << 8) + y) << 8) + xc) * 64 + cg * 8);
            *(uint4*)&sx[(dy * 66 + px) * CPITCH + cg * 8] = d;
        }
    }

    s16x8 breg[18];
#pragma unroll
    for (int kb = 0; kb < 18; ++kb)
        breg[kb] = *(const s16x8*)(woffB + (kb * 64 + L) * 8);
    __syncthreads();

    f32x4 acc = {0.f, 0.f, 0.f, 0.f};
    __builtin_amdgcn_s_setprio(1);
#pragma unroll
    for (int kb = 0; kb < 18; ++kb) {
        int tap = kb >> 1;
        int dy = tap / 3, dxl = tap % 3;         // stage col 0 == w0-1
        int pxl = v * 16 + col + dxl;
        int ci0 = ((kb & 1) << 5) + quad * 8;
        s16x8 a = *(const s16x8*)&sx[(dy * 66 + pxl) * CPITCH + ci0];
        acc = __builtin_amdgcn_mfma_f32_16x16x32_f16(a, breg[kb], acc, 0, 0, 0);
    }
    __builtin_amdgcn_s_setprio(0);
    int oc = col;                         // D col
    float bo = b_off[oc];
    float s = 0.f, s2 = 0.f;
#pragma unroll
    for (int r = 0; r < 4; ++r) {
        float val = acc[r] + bo;
        if (oc < NOFF) {
            int w = w0 + v * 16 + quad * 4 + r;  // D row
            __half hv = __float2half(val);
            off_raw[((b * NOFF + oc) << 16) + (h << 8) + w] = *(unsigned short*)&hv;
        }
        s += val; s2 += val * val;
    }
    s  += __shfl_xor(s, 16, 64);  s  += __shfl_xor(s, 32, 64);
    s2 += __shfl_xor(s2, 16, 64); s2 += __shfl_xor(s2, 32, 64);
    if (quad == 0) { rs[v][oc] = s; rs2[v][oc] = s2; }
    __syncthreads();
    if (t < NOFF) {   // banked atomic accumulation: slot (b<<6)|bank, idx g*2+{0,1}
        float a_ = rs[0][t] + rs[1][t] + rs[2][t] + rs[3][t];
        float a2 = rs2[0][t] + rs2[1][t] + rs2[2][t] + rs2[3][t];
        float* dst = sums_off + ((b << 6) + (blockIdx.x & 63)) * 32 + (t >> 1) * 2;
        atomicAdd(&dst[0], a_);
        atomicAdd(&dst[1], a2);
    }
}

// ---------------- fused main: GN+tanh+cumsum -> fp16 packed lerp -> MFMA -> GN sums via banked atomics ----------------
// LDS 22,144 B; 4 rounds of 16 px; XCD band swizzle; free allocator (no waves-per-eu attr)
__global__ __launch_bounds__(256) void main_mfma(const unsigned short* __restrict__ xTh,
                                                 const unsigned short* __restrict__ off_raw,
                                                 const float* __restrict__ sums_off,
                                                 const float* __restrict__ gno_w,
                                                 const float* __restrict__ gno_b,
                                                 const unsigned short* __restrict__ wdscB,
                                                 const float* __restrict__ b_dsc,
                                                 unsigned short* __restrict__ tmph,
                                                 float* __restrict__ sums_out) {
    __shared__ unsigned short aT[16 * 584];   // 18,688 B: 16 px rows, pitch 584 halves
    __shared__ unsigned       offs[576];      //  2,304 B: full elem offset (cg=0), 23 bits
    __shared__ unsigned short fys[576];       //  1,152 B: fy as fp16 bits

    int t = threadIdx.x;
    int L = t & 63, nt = t >> 6;
    int b, h, wt;
    swizzle_bhw(blockIdx.x, b, h, wt);
    int w0 = wt << 6;
    int bBase = b << 22;                  // b * 256*256*64

    // Phase A: 64 threads; lane t reads bank t's partial sums, shfl-tree reduces,
    // then one pixel each: GN+tanh -> outward cumsum -> precomputed offsets
    if (t < 64) {
        float sv[10];
        const float* p = sums_off + ((b << 6) + t) * 32;
#pragma unroll
        for (int i = 0; i < 10; ++i) sv[i] = p[i];
#pragma unroll
        for (int o = 1; o <= 32; o <<= 1) {
#pragma unroll
            for (int i = 0; i < 10; ++i) sv[i] += __shfl_xor(sv[i], o, 64);
        }
        float msg[5], rsg[5];
#pragma unroll
        for (int g = 0; g < 5; ++g) {
            float mean = sv[g * 2] * (1.f / 131072.f);
            float var  = sv[g * 2 + 1] * (1.f / 131072.f) - mean * mean;
            msg[g] = mean;
            rsg[g] = rsqrtf(var + 1e-5f);
        }
        int w = w0 + t;
        float tk[9];
#pragma unroll
        for (int k = 0; k < 9; ++k) {
            unsigned short u = off_raw[((b * NOFF + k) << 16) + (h << 8) + w];
            float vv = __half2float(*(__half*)&u);
            int g = k >> 1;
            tk[k] = fast_tanh((vv - msg[g]) * rsg[g] * gno_w[k] + gno_b[k]);
        }
        float yc[9];
        float c = 0.f;
#pragma unroll
        for (int k = 3; k >= 0; --k) { c += tk[k]; yc[k] = c; }
        yc[4] = 0.f;
        c = 0.f;
#pragma unroll
        for (int k = 5; k < 9; ++k) { c += tk[k]; yc[k] = c; }
#pragma unroll
        for (int k = 0; k < 9; ++k) {
            float y = fminf(fmaxf((float)h + yc[k], 0.f), 255.f);
            float y0f = floorf(y);
            int y0 = (int)y0f;
            int xc = min(max(w + k - 4, 0), 255);
            __half fh = __float2half(y - y0f);
            offs[t * 9 + k] = (unsigned)(bBase + (y0 << 14) + (xc << 6));
            fys[t * 9 + k]  = *(unsigned short*)&fh;
        }
    }

    s16x8 wreg[18];
#pragma unroll
    for (int kb = 0; kb < 18; ++kb)
        wreg[kb] = *(const s16x8*)(wdscB + ((nt * 18 + kb) * 64 + L) * 8);

    int col = L & 15, quad = L >> 4;
    int co = nt * 16 + col;
    float bias = b_dsc[co];
    float ss = 0.f, ss2 = 0.f;

    for (int round = 0; round < 4; ++round) {
        __syncthreads();   // offs/fys ready (round 0) / aT reads of prev round done
        // stage 16 px: 16*9*8 = 1152 chunk-items, 4.5 iters
#pragma unroll
        for (int it = 0; it < 5; ++it) {
            int idx = it * 256 + t;
            if (idx < 1152) {
                int cg  = idx & 7;
                int r2  = idx >> 3;            // 0..143
                int pxl = r2 / 9;
                int k   = r2 - pxl * 9;
                int pi  = (round * 16 + pxl) * 9 + k;
                unsigned o0 = offs[pi] + (cg << 3);
                unsigned short fb = fys[pi];
                unsigned o1 = fb ? o0 + 16384 : o0;  // +1 row (256*64) iff fy != 0
                __half fh = *(__half*)&fb;
                __half2 fy2 = __half2half2(fh);
                uint4 u0 = *(const uint4*)(xTh + o0);
                uint4 u1 = *(const uint4*)(xTh + o1);
                uint4 d;
                d.x = lerp2h(u0.x, u1.x, fy2);
                d.y = lerp2h(u0.y, u1.y, fy2);
                d.z = lerp2h(u0.z, u1.z, fy2);
                d.w = lerp2h(u0.w, u1.w, fy2);
                int c2 = (cg + k) & 7;
                *(uint4*)&aT[pxl * 584 + k * 64 + c2 * 8] = d;
            }
        }
        __syncthreads();

        {
            int row = col;                 // A row = pixel within the 16 staged
            f32x4 acc = {0.f, 0.f, 0.f, 0.f};
            __builtin_amdgcn_s_setprio(1);
#pragma unroll
            for (int kb = 0; kb < 18; ++kb) {
                int k  = kb >> 1;
                int cch = ((kb & 1) << 2) + quad;
                int c2 = (cch + k) & 7;
                s16x8 a = *(const s16x8*)&aT[row * 584 + k * 64 + c2 * 8];
                acc = __builtin_amdgcn_mfma_f32_16x16x32_f16(a, wreg[kb], acc, 0, 0, 0);
            }
            __builtin_amdgcn_s_setprio(0);
            // blocked tmph write: lane packs its 4 px (r=0..3) of channel co into
            // one uint2; quad group (16 lanes) = one full 128B line, written once.
            int wblk = (w0 >> 2) + round * 4 + quad;
            size_t ebase = ((size_t)(((b << 8) + h) << 6) + wblk) * 64 + co;  // uint2 cells
            float v0 = acc[0] + bias, v1 = acc[1] + bias;
            float v2 = acc[2] + bias, v3 = acc[3] + bias;
            ss  += v0 + v1 + v2 + v3;
            ss2 += v0 * v0 + v1 * v1 + v2 * v2 + v3 * v3;
            __half2 p0 = __floats2half2_rn(v0, v1);
            __half2 p1 = __floats2half2_rn(v2, v3);
            uint2 pk;
            pk.x = *(unsigned*)&p0;
            pk.y = *(unsigned*)&p1;
            ((uint2*)tmph)[ebase] = pk;
        }
    }
    // per-block GN partials: sum over 64 px (quads) then over the 4 channels of each group
    ss  += __shfl_xor(ss, 16, 64);  ss  += __shfl_xor(ss, 32, 64);
    ss2 += __shfl_xor(ss2, 16, 64); ss2 += __shfl_xor(ss2, 32, 64);
    float sg = ss, sg2 = ss2;
    sg  += __shfl_xor(sg, 1, 64);  sg  += __shfl_xor(sg, 2, 64);
    sg2 += __shfl_xor(sg2, 1, 64); sg2 += __shfl_xor(sg2, 2, 64);
    if (quad == 0 && (col & 3) == 0) {
        int gi = nt * 4 + (col >> 2);      // 0..15
        float* dst = sums_out + ((b << 6) + (blockIdx.x & 63)) * 32 + gi * 2;
        atomicAdd(&dst[0], sg);
        atomicAdd(&dst[1], sg2);
    }
}

// ---------------- final: blocked tmph -> bank-reduce stats -> GN -> ReLU -> NCHW fp32 out ----------------
__global__ __launch_bounds__(256) void apply_final_kernel(const unsigned short* __restrict__ tmph,
                                                          const float* __restrict__ sums_out,
                                                          const float* __restrict__ gn_w,
                                                          const float* __restrict__ gn_b,
                                                          float* __restrict__ out) {
    __shared__ float tile[64 * 65];      // [c][w] pitch 65
    __shared__ float statsS[32];         // raw sums for our b: gi*2 + {0,1}
    int wt = blockIdx.x & 3;
    int h  = (blockIdx.x >> 2) & 255;
    int b  = blockIdx.x >> 10;
    int w0 = wt * 64;
    int t  = threadIdx.x;
    {   // bank reduction: value i8 summed over 64 banks by 8 threads each
        int i8 = t >> 3, sb = t & 7;
        float s = 0.f;
#pragma unroll
        for (int bk = sb; bk < 64; bk += 8)
            s += sums_out[((b << 6) + bk) * 32 + i8];
        s += __shfl_xor(s, 1, 64); s += __shfl_xor(s, 2, 64); s += __shfl_xor(s, 4, 64);
        if (sb == 0) statsS[i8] = s;
    }
    __syncthreads();
    {   // load blocked tmph: thread = (co, wb); uint2 = 4 px of channel co (512B/instr)
        int co = t & 63, wb0 = t >> 6;
        int g = co >> 2;
        float s0 = statsS[g * 2], s1 = statsS[g * 2 + 1];
        float mean = s0 * (1.f / 262144.f);
        float var  = s1 * (1.f / 262144.f) - mean * mean;
        float rstd = rsqrtf(var + 1e-5f);
        float sc = rstd * gn_w[co];
        float sh = gn_b[co] - mean * sc;
        const uint2* src = (const uint2*)tmph;
#pragma unroll
        for (int it = 0; it < 4; ++it) {
            int wb = wb0 + it * 4;
            size_t bp = (size_t)(((b << 8) + h) << 6) + (w0 >> 2) + wb;
            uint2 u = src[bp * 64 + co];
            float2 f0 = __half22float2(*(__half2*)&u.x);
            float2 f1 = __half22float2(*(__half2*)&u.y);
            float* dst = &tile[co * 65 + wb * 4];
            dst[0] = fmaxf(fmaf(f0.x, sc, sh), 0.f);
            dst[1] = fmaxf(fmaf(f0.y, sc, sh), 0.f);
            dst[2] = fmaxf(fmaf(f1.x, sc, sh), 0.f);
            dst[3] = fmaxf(fmaf(f1.y, sc, sh), 0.f);
        }
    }
    __syncthreads();
    {   // store: float4 over w (16 lanes * 16B = 256B contiguous; wave = 1KB/instr)
        int wq = t & 15, c0 = t >> 4;
#pragma unroll
        for (int it = 0; it < 4; ++it) {
            int co = c0 + it * 16;
            const float* row = &tile[co * 65 + wq * 4];
            float4 v;
            v.x = row[0]; v.y = row[1]; v.z = row[2]; v.w = row[3];
            *(float4*)&out[((size_t)(b * CC + co) * HH + h) * WW + w0 + wq * 4] = v;
        }
    }
}

extern "C" void kernel_launch(void* const* d_in, const int* in_sizes, int n_in,
                              void* d_out, int out_size, void* d_ws, size_t ws_size,
                              hipStream_t stream) {
    const float* x     = (const float*)d_in[0];
    const float* w_off = (const float*)d_in[1];
    const float* b_off = (const float*)d_in[2];
    const float* gno_w = (const float*)d_in[3];
    const float* gno_b = (const float*)d_in[4];
    const float* w_dsc = (const float*)d_in[5];
    const float* b_dsc = (const float*)d_in[6];
    const float* gn_w  = (const float*)d_in[7];
    const float* gn_b  = (const float*)d_in[8];
    float* out = (float*)d_out;

    char* ws = (char*)d_ws;
    unsigned short* xTh     = (unsigned short*)(ws);               // 16,777,216 B
    unsigned short* tmph    = (unsigned short*)(ws + 16777216);    // 16,777,216 B (blocked layout)
    unsigned short* off_raw = (unsigned short*)(ws + 33554432);    //  2,621,440 B (fp16)
    unsigned short* wdscB   = (unsigned short*)(ws + 36175872);    //     73,728 B
    unsigned short* woffB   = (unsigned short*)(ws + 36249600);    //     18,432 B
    float* sums_off         = (float*)(ws + 36268032);             //     16,384 B (128 slots x 32 f)
    float* sums_out         = (float*)(ws + 36284416);             //     16,384 B (128 slots x 32 f)

    hipLaunchKernelGGL(transpose_x_kernel, dim3(2192), dim3(256), 0, stream,
                       x, xTh, w_off, w_dsc, woffB, wdscB, sums_off, sums_out);
    hipLaunchKernelGGL(conv_off_mfma, dim3(2048), dim3(256), 0, stream,
                       xTh, woffB, b_off, off_raw, sums_off);
    hipLaunchKernelGGL(main_mfma, dim3(2048), dim3(256), 0, stream,
                       xTh, off_raw, sums_off, gno_w, gno_b, wdscB, b_dsc,
                       tmph, sums_out);
    hipLaunchKernelGGL(apply_final_kernel, dim3(2048), dim3(256), 0, stream,
                       tmph, sums_out, gn_w, gn_b, out);
}

// Round 9
// 147.212 us; speedup vs baseline: 1.0580x; 1.0580x over previous
//
#include <hip/hip_runtime.h>
#include <hip/hip_fp16.h>
#include <math.h>

#define BB 2
#define CC 64
#define HH 256
#define WW 256
#define KK 9
#define NOFF 10          // offset channels needed (0..8 sampled, 9 completes GN group 4)
#define HW (HH*WW)

typedef __attribute__((ext_vector_type(8))) short s16x8;   // 8 fp16 = 4 VGPRs (MFMA A/B frag)
typedef __attribute__((ext_vector_type(4))) float f32x4;   // MFMA C/D frag

// lerp two packed-fp16 pairs: d = a + fy*(b-a)   (2 VALU: v_pk_sub + v_pk_fma)
__device__ __forceinline__ unsigned lerp2h(unsigned a, unsigned b, __half2 fy2) {
    __half2 ah = *(__half2*)&a, bh = *(__half2*)&b;
    __half2 d = __hfma2(fy2, __hsub2(bh, ah), ah);
    return *(unsigned*)&d;
}

// fast tanh: 1 - 2/(2^(x*2*log2e)+1); v_exp_f32 + v_rcp_f32, saturates correctly
__device__ __forceinline__ float fast_tanh(float z) {
    float e = __builtin_amdgcn_exp2f(z * 2.885390081777927f);
    return 1.f - 2.f * __builtin_amdgcn_rcpf(e + 1.f);
}

// XCD band swizzle: assume xcd = blockIdx % 8 (round-robin dispatch). Give each
// XCD a contiguous 64-row h-band so its resident blocks share a small rolling
// row window in its private 4 MB L2. Decode: W = xcd*256 + i -> (b, h, wt).
__device__ __forceinline__ void swizzle_bhw(int g, int& b, int& h, int& wt) {
    int W = ((g & 7) << 8) | (g >> 3);
    b  = W >> 10;
    int rem = W & 1023;
    h  = rem >> 2;
    wt = rem & 3;
}

// Banked GN accumulators: slot = (b<<6)|bank, 32 floats (128B line) per slot.
// tmph layout: [b][h][wblk=w>>2][co][w&3] fp16; quad group = one full 128B line.

// R8 post-mortem: occupancy pinned ~8 waves/CU across ALL resource configs ->
// residency is not the lever. dur = 13.5K cyc/block = the staging loop's
// serialized per-item chain (ds_read offs -> addr -> 2 global loads -> lerp ->
// ds_write, ~500cy x 4.5 items x 4 rounds + Phase A).
// R9: register-resident coords (uint2 coordP), batched load issue (all 10
// loads of a round back-to-back = ONE latency exposure), and round r+1's
// coord-read+load-issue placed between round r's barriers (hidden under MFMA).
// Only round 0's latency is exposed.

// ---------------- transpose x: NCHW fp32 -> NHWC fp16 ; blocks >= 2048 pack weights + zero sums ----------------
__global__ __launch_bounds__(256) void transpose_x_kernel(const float* __restrict__ x,
                                                          unsigned short* __restrict__ xTh,
                                                          const float* __restrict__ w_off,
                                                          const float* __restrict__ w_dsc,
                                                          unsigned short* __restrict__ woffB,
                                                          unsigned short* __restrict__ wdscB,
                                                          float* __restrict__ sums_off,
                                                          float* __restrict__ sums_out) {
    if (blockIdx.x >= 2048) {            // ---- weight packing (144 blocks) ----
        int idx = (blockIdx.x - 2048) * 256 + threadIdx.x;
        if (blockIdx.x == 2048) {        // zero banked GN accumulators (ws is poisoned)
            int t = threadIdx.x;
            for (int i = t; i < 128 * 32; i += 256) sums_off[i] = 0.f;
            for (int i = t; i < 128 * 32; i += 256) sums_out[i] = 0.f;
        }
        if (idx < 18 * 64 * 8) {
            int kb = idx >> 9;
            int L  = (idx >> 3) & 63;
            int j  = idx & 7;
            int n = L & 15, quad = L >> 4;
            int kk = kb * 32 + quad * 8 + j;
            int tap = kk >> 6, ci = kk & 63;
            float v = (n < NOFF) ? w_off[(n * 64 + ci) * 9 + tap] : 0.f;
            __half hv = __float2half(v);
            woffB[idx] = *(unsigned short*)&hv;
        }
        if (idx < 4 * 18 * 64 * 8) {
            int nt = idx / 9216;
            int r  = idx - nt * 9216;
            int kb = r >> 9;
            int L  = (r >> 3) & 63;
            int j  = r & 7;
            int n = L & 15, quad = L >> 4;
            int co = nt * 16 + n;
            int kk = kb * 32 + quad * 8 + j;
            int k = kk >> 6, ci = kk & 63;
            __half hv = __float2half(w_dsc[(co * 64 + ci) * 9 + k]);
            wdscB[idx] = *(unsigned short*)&hv;
        }
        return;
    }
    __shared__ float tile[64 * 65];      // [w][c] pitch 65
    int wt = blockIdx.x & 3;
    int h  = (blockIdx.x >> 2) & 255;
    int b  = blockIdx.x >> 10;
    int w0 = wt * 64;
    int t  = threadIdx.x;
    {   // load: float4 over w (16 lanes * 16B = 256B contiguous; wave = 1KB/instr)
        int wq = t & 15, c0 = t >> 4;
#pragma unroll
        for (int it = 0; it < 4; ++it) {
            int c = c0 + it * 16;
            float4 v = *(const float4*)&x[(((b * CC + c) * HH + h) * WW) + w0 + wq * 4];
            tile[(wq * 4 + 0) * 65 + c] = v.x;
            tile[(wq * 4 + 1) * 65 + c] = v.y;
            tile[(wq * 4 + 2) * 65 + c] = v.z;
            tile[(wq * 4 + 3) * 65 + c] = v.w;
        }
    }
    __syncthreads();
    {   // store: uint4 = 8 fp16 channels per thread (8 lanes * 16B = 128B contiguous)
        int c8 = t & 7, wr = t >> 3;
        uint4* dst = (uint4*)xTh;
#pragma unroll
        for (int it = 0; it < 2; ++it) {
            int wl = wr + it * 32;
            const float* row = &tile[wl * 65 + c8 * 8];
            __half2 p0 = __floats2half2_rn(row[0], row[1]);
            __half2 p1 = __floats2half2_rn(row[2], row[3]);
            __half2 p2 = __floats2half2_rn(row[4], row[5]);
            __half2 p3 = __floats2half2_rn(row[6], row[7]);
            uint4 d;
            d.x = *(unsigned*)&p0; d.y = *(unsigned*)&p1;
            d.z = *(unsigned*)&p2; d.w = *(unsigned*)&p3;
            dst[((size_t)((b * HH + h) * WW) + w0 + wl) * 8 + c8] = d;
        }
    }
}

// ---------------- offset conv 3x3 via MFMA, LDS-staged halo strip; GN sums via banked atomics ----------------
#define CPITCH 72   // halves per pixel in conv LDS (16B-aligned, 2-way-free bank phase)
__global__ __launch_bounds__(256) void conv_off_mfma(const unsigned short* __restrict__ xTh,
                                                     const unsigned short* __restrict__ woffB,
                                                     const float* __restrict__ b_off,
                                                     unsigned short* __restrict__ off_raw,
                                                     float* __restrict__ sums_off) {
    __shared__ unsigned short sx[3 * 66 * CPITCH];   // 28,512 B
    __shared__ float rs[4][16], rs2[4][16];
    int t = threadIdx.x;
    int L = t & 63, v = t >> 6;
    int b, h, wt;
    swizzle_bhw(blockIdx.x, b, h, wt);
    int w0 = wt << 6;
    int col = L & 15, quad = L >> 4;

    // stage rows h-1..h+1, cols w0-1..w0+64, 64 ch fp16, zero-padded OOB
#pragma unroll
    for (int it = 0; it < 7; ++it) {
        int linear = it * 256 + t;
        if (linear < 1584) {                     // 3*66*8 chunk-items
            int dy  = linear / 528;
            int rem = linear - dy * 528;
            int px  = rem >> 3, cg = rem & 7;
            int y  = h - 1 + dy;
            int xc = w0 - 1 + px;
            uint4 d = make_uint4(0, 0, 0, 0);
            if ((unsigned)y < 256u && (unsigned)xc < 256u)
                d = *(const uint4*)(xTh + ((size_t)(((b << 8) + y) << 8) + xc) * 64 + cg * 8);
            *(uint4*)&sx[(dy * 66 + px) * CPITCH + cg * 8] = d;
        }
    }

    s16x8 breg[18];
#pragma unroll
    for (int kb = 0; kb < 18; ++kb)
        breg[kb] = *(const s16x8*)(woffB + (kb * 64 + L) * 8);
    __syncthreads();

    f32x4 acc = {0.f, 0.f, 0.f, 0.f};
    __builtin_amdgcn_s_setprio(1);
#pragma unroll
    for (int kb = 0; kb < 18; ++kb) {
        int tap = kb >> 1;
        int dy = tap / 3, dxl = tap % 3;         // stage col 0 == w0-1
        int pxl = v * 16 + col + dxl;
        int ci0 = ((kb & 1) << 5) + quad * 8;
        s16x8 a = *(const s16x8*)&sx[(dy * 66 + pxl) * CPITCH + ci0];
        acc = __builtin_amdgcn_mfma_f32_16x16x32_f16(a, breg[kb], acc, 0, 0, 0);
    }
    __builtin_amdgcn_s_setprio(0);
    int oc = col;                         // D col
    float bo = b_off[oc];
    float s = 0.f, s2 = 0.f;
#pragma unroll
    for (int r = 0; r < 4; ++r) {
        float val = acc[r] + bo;
        if (oc < NOFF) {
            int w = w0 + v * 16 + quad * 4 + r;  // D row
            __half hv = __float2half(val);
            off_raw[((b * NOFF + oc) << 16) + (h << 8) + w] = *(unsigned short*)&hv;
        }
        s += val; s2 += val * val;
    }
    s  += __shfl_xor(s, 16, 64);  s  += __shfl_xor(s, 32, 64);
    s2 += __shfl_xor(s2, 16, 64); s2 += __shfl_xor(s2, 32, 64);
    if (quad == 0) { rs[v][oc] = s; rs2[v][oc] = s2; }
    __syncthreads();
    if (t < NOFF) {   // banked atomic accumulation: slot (b<<6)|bank, idx g*2+{0,1}
        float a_ = rs[0][t] + rs[1][t] + rs[2][t] + rs[3][t];
        float a2 = rs2[0][t] + rs2[1][t] + rs2[2][t] + rs2[3][t];
        float* dst = sums_off + ((b << 6) + (blockIdx.x & 63)) * 32 + (t >> 1) * 2;
        atomicAdd(&dst[0], a_);
        atomicAdd(&dst[1], a2);
    }
}

// ---------------- fused main: GN+tanh+cumsum -> reg-coord batched gather -> MFMA -> GN sums ----------------
// LDS 23,296 B; 4 rounds of 16 px; coord/load prefetch hidden under prior round's MFMA
__global__ __launch_bounds__(256) void main_mfma(const unsigned short* __restrict__ xTh,
                                                 const unsigned short* __restrict__ off_raw,
                                                 const float* __restrict__ sums_off,
                                                 const float* __restrict__ gno_w,
                                                 const float* __restrict__ gno_b,
                                                 const unsigned short* __restrict__ wdscB,
                                                 const float* __restrict__ b_dsc,
                                                 unsigned short* __restrict__ tmph,
                                                 float* __restrict__ sums_out) {
    __shared__ unsigned short aT[16 * 584];   // 18,688 B: 16 px rows, pitch 584 halves
    __shared__ uint2 coordP[576];             //  4,608 B: {elem offset (cg=0), fy16}

    int t = threadIdx.x;
    int L = t & 63, nt = t >> 6;
    int b, h, wt;
    swizzle_bhw(blockIdx.x, b, h, wt);
    int w0 = wt << 6;
    int bBase = b << 22;                  // b * 256*256*64

    // Phase A: 64 threads; bank-reduce GN sums, then one pixel each:
    // GN+tanh -> outward cumsum -> packed (offset, fy) coords
    if (t < 64) {
        float sv[10];
        const float* p = sums_off + ((b << 6) + t) * 32;
#pragma unroll
        for (int i = 0; i < 10; ++i) sv[i] = p[i];
#pragma unroll
        for (int o = 1; o <= 32; o <<= 1) {
#pragma unroll
            for (int i = 0; i < 10; ++i) sv[i] += __shfl_xor(sv[i], o, 64);
        }
        float msg[5], rsg[5];
#pragma unroll
        for (int g = 0; g < 5; ++g) {
            float mean = sv[g * 2] * (1.f / 131072.f);
            float var  = sv[g * 2 + 1] * (1.f / 131072.f) - mean * mean;
            msg[g] = mean;
            rsg[g] = rsqrtf(var + 1e-5f);
        }
        int w = w0 + t;
        float tk[9];
#pragma unroll
        for (int k = 0; k < 9; ++k) {
            unsigned short u = off_raw[((b * NOFF + k) << 16) + (h << 8) + w];
            float vv = __half2float(*(__half*)&u);
            int g = k >> 1;
            tk[k] = fast_tanh((vv - msg[g]) * rsg[g] * gno_w[k] + gno_b[k]);
        }
        float yc[9];
        float c = 0.f;
#pragma unroll
        for (int k = 3; k >= 0; --k) { c += tk[k]; yc[k] = c; }
        yc[4] = 0.f;
        c = 0.f;
#pragma unroll
        for (int k = 5; k < 9; ++k) { c += tk[k]; yc[k] = c; }
#pragma unroll
        for (int k = 0; k < 9; ++k) {
            float y = fminf(fmaxf((float)h + yc[k], 0.f), 255.f);
            float y0f = floorf(y);
            int y0 = (int)y0f;
            int xc = min(max(w + k - 4, 0), 255);
            __half fh = __float2half(y - y0f);
            coordP[t * 9 + k] = make_uint2((unsigned)(bBase + (y0 << 14) + (xc << 6)),
                                           (unsigned)(*(unsigned short*)&fh));
        }
    }

    s16x8 wreg[18];
#pragma unroll
    for (int kb = 0; kb < 18; ++kb)
        wreg[kb] = *(const s16x8*)(wdscB + ((nt * 18 + kb) * 64 + L) * 8);

    int col = L & 15, quad = L >> 4;
    int co = nt * 16 + col;
    float bias = b_dsc[co];
    float ss = 0.f, ss2 = 0.f;

    // staging item geometry (fixed per thread): item (round, it) has linear id
    // idx = it*256 + t -> cg = t&7, r2 = it*32 + (t>>3); valid iff r2 < 144
    // (wave-uniform: it==4 valid only for waves 0-1). coordP index = r*144 + r2.
    int tt = t >> 3, cg = t & 7;
    int r2a[5], wadr[5];
#pragma unroll
    for (int it = 0; it < 5; ++it) {
        int r2 = it * 32 + tt;
        r2a[it] = r2;
        int pxl = r2 / 9, k = r2 - pxl * 9;
        wadr[it] = pxl * 584 + k * 64 + (((cg + k) & 7) << 3);
    }

    uint2 rc[5];
    uint4 u0[5], u1[5];

    // issue all 10 loads of round rr back-to-back (one latency exposure)
    auto issue = [&](int rr) {
#pragma unroll
        for (int it = 0; it < 5; ++it) {
            if (it < 4 || t < 128) {
                uint2 c2v = coordP[rr * 144 + r2a[it]];
                rc[it] = c2v;
                unsigned o0 = c2v.x + (cg << 3);
                unsigned o1 = c2v.y ? o0 + 16384 : o0;  // +1 row iff fy != 0
                u0[it] = *(const uint4*)(xTh + o0);
                u1[it] = *(const uint4*)(xTh + o1);
            }
        }
    };
    // lerp + aT write for the in-flight round
    auto consume = [&]() {
#pragma unroll
        for (int it = 0; it < 5; ++it) {
            if (it < 4 || t < 128) {
                unsigned short fb = (unsigned short)rc[it].y;
                __half fh = *(__half*)&fb;
                __half2 fy2 = __half2half2(fh);
                uint4 d;
                d.x = lerp2h(u0[it].x, u1[it].x, fy2);
                d.y = lerp2h(u0[it].y, u1[it].y, fy2);
                d.z = lerp2h(u0[it].z, u1[it].z, fy2);
                d.w = lerp2h(u0[it].w, u1[it].w, fy2);
                *(uint4*)&aT[wadr[it]] = d;
            }
        }
    };

    __syncthreads();      // coordP ready
    issue(0);             // only round 0's load latency is exposed

    for (int r = 0; r < 4; ++r) {
        consume();        // lerp + ds_write aT (round r)
        __syncthreads();  // aT ready for MFMA
        if (r < 3) issue(r + 1);   // coord-read + load issue hidden under MFMA

        {
            int row = col;                 // A row = pixel within the 16 staged
            f32x4 acc = {0.f, 0.f, 0.f, 0.f};
            __builtin_amdgcn_s_setprio(1);
#pragma unroll
            for (int kb = 0; kb < 18; ++kb) {
                int k  = kb >> 1;
                int cch = ((kb & 1) << 2) + quad;
                int c2 = (cch + k) & 7;
                s16x8 a = *(const s16x8*)&aT[row * 584 + k * 64 + c2 * 8];
                acc = __builtin_amdgcn_mfma_f32_16x16x32_f16(a, wreg[kb], acc, 0, 0, 0);
            }
            __builtin_amdgcn_s_setprio(0);
            // blocked tmph write: lane packs its 4 px of channel co into one uint2;
            // quad group (16 lanes) = one full 128B line, written once.
            int wblk = (w0 >> 2) + r * 4 + quad;
            size_t ebase = ((size_t)(((b << 8) + h) << 6) + wblk) * 64 + co;  // uint2 cells
            float v0 = acc[0] + bias, v1 = acc[1] + bias;
            float v2 = acc[2] + bias, v3 = acc[3] + bias;
            ss  += v0 + v1 + v2 + v3;
            ss2 += v0 * v0 + v1 * v1 + v2 * v2 + v3 * v3;
            __half2 p0 = __floats2half2_rn(v0, v1);
            __half2 p1 = __floats2half2_rn(v2, v3);
            uint2 pk;
            pk.x = *(unsigned*)&p0;
            pk.y = *(unsigned*)&p1;
            ((uint2*)tmph)[ebase] = pk;
        }
        if (r < 3) __syncthreads();   // aT consumed before next round's writes
    }
    // per-block GN partials: sum over 64 px (quads) then over the 4 channels of each group
    ss  += __shfl_xor(ss, 16, 64);  ss  += __shfl_xor(ss, 32, 64);
    ss2 += __shfl_xor(ss2, 16, 64); ss2 += __shfl_xor(ss2, 32, 64);
    float sg = ss, sg2 = ss2;
    sg  += __shfl_xor(sg, 1, 64);  sg  += __shfl_xor(sg, 2, 64);
    sg2 += __shfl_xor(sg2, 1, 64); sg2 += __shfl_xor(sg2, 2, 64);
    if (quad == 0 && (col & 3) == 0) {
        int gi = nt * 4 + (col >> 2);      // 0..15
        float* dst = sums_out + ((b << 6) + (blockIdx.x & 63)) * 32 + gi * 2;
        atomicAdd(&dst[0], sg);
        atomicAdd(&dst[1], sg2);
    }
}

// ---------------- final: blocked tmph -> bank-reduce stats -> GN -> ReLU -> NCHW fp32 out ----------------
__global__ __launch_bounds__(256) void apply_final_kernel(const unsigned short* __restrict__ tmph,
                                                          const float* __restrict__ sums_out,
                                                          const float* __restrict__ gn_w,
                                                          const float* __restrict__ gn_b,
                                                          float* __restrict__ out) {
    __shared__ float tile[64 * 65];      // [c][w] pitch 65
    __shared__ float statsS[32];         // raw sums for our b: gi*2 + {0,1}
    int wt = blockIdx.x & 3;
    int h  = (blockIdx.x >> 2) & 255;
    int b  = blockIdx.x >> 10;
    int w0 = wt * 64;
    int t  = threadIdx.x;
    {   // bank reduction: value i8 summed over 64 banks by 8 threads each
        int i8 = t >> 3, sb = t & 7;
        float s = 0.f;
#pragma unroll
        for (int bk = sb; bk < 64; bk += 8)
            s += sums_out[((b << 6) + bk) * 32 + i8];
        s += __shfl_xor(s, 1, 64); s += __shfl_xor(s, 2, 64); s += __shfl_xor(s, 4, 64);
        if (sb == 0) statsS[i8] = s;
    }
    __syncthreads();
    {   // load blocked tmph: thread = (co, wb); uint2 = 4 px of channel co (512B/instr)
        int co = t & 63, wb0 = t >> 6;
        int g = co >> 2;
        float s0 = statsS[g * 2], s1 = statsS[g * 2 + 1];
        float mean = s0 * (1.f / 262144.f);
        float var  = s1 * (1.f / 262144.f) - mean * mean;
        float rstd = rsqrtf(var + 1e-5f);
        float sc = rstd * gn_w[co];
        float sh = gn_b[co] - mean * sc;
        const uint2* src = (const uint2*)tmph;
#pragma unroll
        for (int it = 0; it < 4; ++it) {
            int wb = wb0 + it * 4;
            size_t bp = (size_t)(((b << 8) + h) << 6) + (w0 >> 2) + wb;
            uint2 u = src[bp * 64 + co];
            float2 f0 = __half22float2(*(__half2*)&u.x);
            float2 f1 = __half22float2(*(__half2*)&u.y);
            float* dst = &tile[co * 65 + wb * 4];
            dst[0] = fmaxf(fmaf(f0.x, sc, sh), 0.f);
            dst[1] = fmaxf(fmaf(f0.y, sc, sh), 0.f);
            dst[2] = fmaxf(fmaf(f1.x, sc, sh), 0.f);
            dst[3] = fmaxf(fmaf(f1.y, sc, sh), 0.f);
        }
    }
    __syncthreads();
    {   // store: float4 over w (16 lanes * 16B = 256B contiguous; wave = 1KB/instr)
        int wq = t & 15, c0 = t >> 4;
#pragma unroll
        for (int it = 0; it < 4; ++it) {
            int co = c0 + it * 16;
            const float* row = &tile[co * 65 + wq * 4];
            float4 v;
            v.x = row[0]; v.y = row[1]; v.z = row[2]; v.w = row[3];
            *(float4*)&out[((size_t)(b * CC + co) * HH + h) * WW + w0 + wq * 4] = v;
        }
    }
}

extern "C" void kernel_launch(void* const* d_in, const int* in_sizes, int n_in,
                              void* d_out, int out_size, void* d_ws, size_t ws_size,
                              hipStream_t stream) {
    const float* x     = (const float*)d_in[0];
    const float* w_off = (const float*)d_in[1];
    const float* b_off = (const float*)d_in[2];
    const float* gno_w = (const float*)d_in[3];
    const float* gno_b = (const float*)d_in[4];
    const float* w_dsc = (const float*)d_in[5];
    const float* b_dsc = (const float*)d_in[6];
    const float* gn_w  = (const float*)d_in[7];
    const float* gn_b  = (const float*)d_in[8];
    float* out = (float*)d_out;

    char* ws = (char*)d_ws;
    unsigned short* xTh     = (unsigned short*)(ws);               // 16,777,216 B
    unsigned short* tmph    = (unsigned short*)(ws + 16777216);    // 16,777,216 B (blocked layout)
    unsigned short* off_raw = (unsigned short*)(ws + 33554432);    //  2,621,440 B (fp16)
    unsigned short* wdscB   = (unsigned short*)(ws + 36175872);    //     73,728 B
    unsigned short* woffB   = (unsigned short*)(ws + 36249600);    //     18,432 B
    float* sums_off         = (float*)(ws + 36268032);             //     16,384 B (128 slots x 32 f)
    float* sums_out         = (float*)(ws + 36284416);             //     16,384 B (128 slots x 32 f)

    hipLaunchKernelGGL(transpose_x_kernel, dim3(2192), dim3(256), 0, stream,
                       x, xTh, w_off, w_dsc, woffB, wdscB, sums_off, sums_out);
    hipLaunchKernelGGL(conv_off_mfma, dim3(2048), dim3(256), 0, stream,
                       xTh, woffB, b_off, off_raw, sums_off);
    hipLaunchKernelGGL(main_mfma, dim3(2048), dim3(256), 0, stream,
                       xTh, off_raw, sums_off, gno_w, gno_b, wdscB, b_dsc,
                       tmph, sums_out);
    hipLaunchKernelGGL(apply_final_kernel, dim3(2048), dim3(256), 0, stream,
                       tmph, sums_out, gn_w, gn_b, out);
}